// Round 13
// baseline (37.621 us; speedup 1.0000x reference)
//
#include <hip/hip_runtime.h>
#include <math.h>

#define NCH 256        // number of simplex chunks (grid_ect = 2*NCH = 512)
#define RSL 8          // reduction slices
#define FPS 32768.0f   // fixed-point scale 2^15 for transition sums

// K1: nh[n][t] = x[n].v[:,t]. One thread per node, 32 outputs via float4.
// Coalesced row stores; x reads sequential. (Proven shape from r7.)
__global__ __launch_bounds__(256) void nh_kernel(const float* __restrict__ x,
    const float* __restrict__ v, float* __restrict__ nh, int N) {
  __shared__ float vs[96];
  int tid = threadIdx.x;
  if (tid < 96) vs[tid] = v[tid];
  __syncthreads();
  int n = blockIdx.x * 256 + tid;
  if (n >= N) return;
  float x0 = x[3 * n], x1 = x[3 * n + 1], x2 = x[3 * n + 2];
  float4* row = (float4*)(nh + (size_t)n * 32);
#pragma unroll
  for (int i = 0; i < 8; ++i) {
    float4 r;
    r.x = fmaf(x0, vs[4 * i + 0], fmaf(x1, vs[32 + 4 * i + 0], x2 * vs[64 + 4 * i + 0]));
    r.y = fmaf(x0, vs[4 * i + 1], fmaf(x1, vs[32 + 4 * i + 1], x2 * vs[64 + 4 * i + 1]));
    r.z = fmaf(x0, vs[4 * i + 2], fmaf(x1, vs[32 + 4 * i + 2], x2 * vs[64 + 4 * i + 2]));
    r.w = fmaf(x0, vs[4 * i + 3], fmaf(x1, vs[32 + 4 * i + 3], x2 * vs[64 + 4 * i + 3]));
    row[i] = r;
  }
}

// K2: raw-order saturation-split ECT reading precomputed nh rows.
// Block = (chunk c, theta-half hf); 1024 threads = (srow 0..63, t16 0..15).
// Per vertex: ONE 64B line (16-theta half-row, coalesced across t16 lanes)
// instead of three random x-lines -> 3x fewer line requests (the r12
// bottleneck). 2 blocks/CU = 8 waves/SIMD (HW max).
// LDS hist [arr][g][bin][t16] = 32 KB; LDS int atomics only (deterministic).
// Flush = plain coalesced int4 stores into partial[bid][8192].
__global__ __launch_bounds__(1024) void ect_kernel(const float* __restrict__ nh,
    const int* __restrict__ ei, const int* __restrict__ face,
    const int* __restrict__ batch, const float* __restrict__ lin,
    const int* __restrict__ scale_p, int* __restrict__ partial,
    int N, int E, int F, int M, int csz) {
  __shared__ alignas(16) int hist[8192];  // arr*4096 + g*512 + bin*16 + t16
  int tid = threadIdx.x, bid = blockIdx.x;
  int c = bid >> 1, hf = bid & 1;
#pragma unroll
  for (int i = 0; i < 2; ++i)
    ((int4*)hist)[tid + 1024 * i] = int4{0, 0, 0, 0};
  __syncthreads();

  int t16 = tid & 15, srow = tid >> 4;    // srow 0..63
  int tt = (hf << 4) + t16;               // global theta
  int start = c * csz;
  int end = min(start + csz, M);

  float scale = (float)scale_p[0];
  float lin0 = lin[0];
  float step = (lin[31] - lin0) * (1.f / 31.f);
  float istep = 1.f / step;
  float Cl = scale * step * 1.44269504088896f;  // log2-slope per bin
  float w = 13.f / (scale * step);              // transition half-width (bins)

  auto hrow = [&](int n) { return nh[(size_t)n * 32 + tt]; };
  auto deposit = [&](float h, int g, int isn) {
    float kf = (h - lin0) * istep;
    int b0 = (int)ceilf(kf - w);
    int b1 = (int)floorf(kf + w);
    int fs = max(b1 + 1, 0);
    int gb = g << 9;
    if (fs <= 31) atomicAdd(&hist[gb + (fs << 4) + t16], isn);
    float q = Cl * kf;
    float fsn = (float)isn;
    int blo = max(b0, 0), bhi = min(b1, 31);
    for (int b = blo; b <= bhi; ++b) {
      float e2 = __builtin_amdgcn_exp2f(fmaf(-Cl, (float)b, q));
      float val = fsn * __builtin_amdgcn_rcpf(1.f + e2);
      atomicAdd(&hist[4096 + gb + (b << 4) + t16], (int)rintf(val * FPS));
    }
  };

  // nodes
  int e0 = min(end, N);
  for (int m = start + srow; m < e0; m += 64)
    deposit(hrow(m), batch[m], 1);
  // edges (max over 2 endpoints, sign -1)
  int s1 = max(start, N), e1 = min(end, N + E);
  for (int m = s1 + srow; m < e1; m += 64) {
    int e = m - N;
    int n0 = ei[e], n1 = ei[E + e];
    deposit(fmaxf(hrow(n0), hrow(n1)), batch[n0], -1);
  }
  // faces (max over 3 vertices, sign +1)
  int s2 = max(start, N + E);
  for (int m = s2 + srow; m < end; m += 64) {
    int f = m - N - E;
    int n0 = face[f], n1 = face[F + f], n2 = face[2 * F + f];
    deposit(fmaxf(fmaxf(hrow(n0), hrow(n1)), hrow(n2)), batch[n0], 1);
  }
  __syncthreads();
  int4* dst = (int4*)(partial + (size_t)bid * 8192);
  const int4* src = (const int4*)hist;
#pragma unroll
  for (int i = 0; i < 2; ++i)
    dst[tid + 1024 * i] = src[tid + 1024 * i];
}

// K3: tree reduce over chunks. 512 blocks: s = bid>>6 (0..7), cg = bid&63;
// cell cid = cg*256+tid; cid = hf*8192 + (arr*4096 + g*512 + bin*16 + t16).
// Plain coalesced loads/stores, no atomics.
__global__ __launch_bounds__(256) void reduce_kernel(const int* __restrict__ partial,
    int* __restrict__ part2) {
  int tid = threadIdx.x, bid = blockIdx.x;
  int s = bid >> 6, cg = bid & 63;
  int cid = cg * 256 + tid;
  int hf = cid >> 13, j = cid & 8191;
  int sum = 0;
  for (int cc = s; cc < NCH; cc += RSL)
    sum += partial[(size_t)(cc * 2 + hf) * 8192 + j];
  part2[s * 16384 + cid] = sum;
}

// K4: per-graph block (8 x 1024): sum RSL slices (plain loads), Hillis-Steele
// prefix of markers over bins, add fractional transitions, per-graph max,
// normalize, write out.
__global__ __launch_bounds__(1024) void fin_kernel(const int* __restrict__ part2,
    float* __restrict__ out) {
  __shared__ float sP[32][33];
  __shared__ float wmax[16];
  int g = blockIdx.x, tid = threadIdx.x;
  int b = tid >> 5, t = tid & 31;
  int hf = t >> 4, t16 = t & 15;
  int jc = (hf << 13) + (g << 9) + (b << 4) + t16;  // marker cell
  int ja = jc + 4096;                               // transition cell
  int sc = 0, sa = 0;
#pragma unroll
  for (int s = 0; s < RSL; ++s) {
    sc += part2[s * 16384 + jc];
    sa += part2[s * 16384 + ja];
  }
  sP[b][t] = (float)sc;
  __syncthreads();
#pragma unroll
  for (int st = 1; st < 32; st <<= 1) {
    float add = (b >= st) ? sP[b - st][t] : 0.f;
    __syncthreads();
    sP[b][t] += add;
    __syncthreads();
  }
  float r = sP[b][t] + (float)sa * (1.f / FPS);
  float m = r;
#pragma unroll
  for (int off = 32; off > 0; off >>= 1) m = fmaxf(m, __shfl_down(m, off));
  if ((tid & 63) == 0) wmax[tid >> 6] = m;
  __syncthreads();
  if (tid == 0) {
    float mm = wmax[0];
#pragma unroll
    for (int ww = 1; ww < 16; ++ww) mm = fmaxf(mm, wmax[ww]);
    wmax[0] = mm;
  }
  __syncthreads();
  out[(size_t)g * 1024 + tid] = r / wmax[0];
}

extern "C" void kernel_launch(void* const* d_in, const int* in_sizes, int n_in,
                              void* d_out, int out_size, void* d_ws, size_t ws_size,
                              hipStream_t stream) {
  const float* x     = (const float*)d_in[0];
  const float* v     = (const float*)d_in[1];
  const float* lin   = (const float*)d_in[2];
  const int*   ei    = (const int*)d_in[3];
  const int*   face  = (const int*)d_in[4];
  const int*   batch = (const int*)d_in[5];
  const int*   scale = (const int*)d_in[6];
  const int N = in_sizes[5];
  const int E = in_sizes[3] / 2;
  const int F = in_sizes[4] / 3;
  const int M = N + E + F;
  const int csz = (M + NCH - 1) / NCH;   // simplices per chunk (~704)

  float* nh    = (float*)d_ws;                         // N*32 f32
  int* partial = (int*)(nh + (size_t)N * 32);          // 2*NCH*8192 ints
  int* part2   = partial + (size_t)2 * NCH * 8192;     // RSL*16384 ints

  nh_kernel<<<(N + 255) / 256, 256, 0, stream>>>(x, v, nh, N);
  ect_kernel<<<2 * NCH, 1024, 0, stream>>>(nh, ei, face, batch, lin, scale,
                                           partial, N, E, F, M, csz);
  reduce_kernel<<<64 * RSL, 256, 0, stream>>>(partial, part2);
  fin_kernel<<<8, 1024, 0, stream>>>(part2, (float*)d_out);
}

// Round 14
// 33.705 us; speedup vs baseline: 1.1162x; 1.1162x over previous
//
#include <hip/hip_runtime.h>
#include <math.h>

#define NCH 256        // number of simplex chunks (grid_ect = 2*NCH = 512)
#define RSL 8          // reduction slices
#define FPS 32768.0f   // fixed-point scale 2^15 for transition sums

// K1: raw-order saturation-split ECT, heights on the fly from x.v (r12 base).
// Block = (chunk c, theta-half hf); 1024 threads = (srow 0..63, t16 0..15).
// 2 blocks/CU = 8 waves/SIMD (HW max; pinned via __launch_bounds__(1024,8)).
// NEW vs r12: 2-way software-pipelined inner loops — both simplices' loads
// issue before either deposit -> 2 concurrent dependent-load chains per
// thread (ect was latency-chain-bound at ILP=1). Deposit simplified: the
// transition window (2w<1) holds at most ONE bin -> b = rint(kf), no loop.
// LDS hist [arr][g][bin][t16] = 32 KB; LDS int atomics only (deterministic).
// Flush = plain coalesced int4 stores into partial[bid][8192].
__global__ __launch_bounds__(1024, 8) void ect_kernel(const float* __restrict__ x,
    const float* __restrict__ v, const int* __restrict__ ei,
    const int* __restrict__ face, const int* __restrict__ batch,
    const float* __restrict__ lin, const int* __restrict__ scale_p,
    int* __restrict__ partial, int N, int E, int F, int M, int csz) {
  __shared__ alignas(16) int hist[8192];  // arr*4096 + g*512 + bin*16 + t16
  int tid = threadIdx.x, bid = blockIdx.x;
  int c = bid >> 1, hf = bid & 1;
#pragma unroll
  for (int i = 0; i < 2; ++i)
    ((int4*)hist)[tid + 1024 * i] = int4{0, 0, 0, 0};
  __syncthreads();

  int t16 = tid & 15, srow = tid >> 4;    // srow 0..63
  int tt = (hf << 4) + t16;               // global theta
  float v0 = v[tt], v1 = v[32 + tt], v2 = v[64 + tt];
  int start = c * csz;
  int end = min(start + csz, M);

  float scale = (float)scale_p[0];
  float lin0 = lin[0];
  float step = (lin[31] - lin0) * (1.f / 31.f);
  float istep = 1.f / step;
  float Cl = scale * step * 1.44269504088896f;  // log2-slope per bin
  float w = 13.f / (scale * step);              // transition half-width (bins)

  auto dot3 = [&](int n) {
    return fmaf(x[3 * n], v0, fmaf(x[3 * n + 1], v1, x[3 * n + 2] * v2));
  };
  auto deposit = [&](float h, int g, int isn) {
    float kf = (h - lin0) * istep;
    int fs = max((int)floorf(kf + w) + 1, 0);
    int gb = g << 9;
    if (fs <= 31) atomicAdd(&hist[gb + (fs << 4) + t16], isn);
    float bf = rintf(kf);
    float d = kf - bf;
    if (fabsf(d) <= w) {
      int b = (int)bf;
      if ((unsigned)b <= 31u) {
        float e2 = __builtin_amdgcn_exp2f(Cl * d);
        float val = (float)isn * __builtin_amdgcn_rcpf(1.f + e2);
        atomicAdd(&hist[4096 + gb + (b << 4) + t16], (int)rintf(val * FPS));
      }
    }
  };

  // nodes
  {
    int e0 = min(end, N);
    int m = start + srow;
    for (; m + 64 < e0; m += 128) {
      float ha = dot3(m);      int ga  = batch[m];
      float hb = dot3(m + 64); int gb2 = batch[m + 64];
      deposit(ha, ga, 1);
      deposit(hb, gb2, 1);
    }
    if (m < e0) deposit(dot3(m), batch[m], 1);
  }
  // edges (max over 2 endpoints, sign -1)
  {
    int s1 = max(start, N), e1 = min(end, N + E);
    int m = s1 + srow;
    for (; m + 64 < e1; m += 128) {
      int ea = m - N, eb = ea + 64;
      int a0 = ei[ea], a1 = ei[E + ea];
      int b0 = ei[eb], b1 = ei[E + eb];
      float ha = fmaxf(dot3(a0), dot3(a1)); int ga  = batch[a0];
      float hb = fmaxf(dot3(b0), dot3(b1)); int gb2 = batch[b0];
      deposit(ha, ga, -1);
      deposit(hb, gb2, -1);
    }
    if (m < e1) {
      int e = m - N;
      int n0 = ei[e], n1 = ei[E + e];
      deposit(fmaxf(dot3(n0), dot3(n1)), batch[n0], -1);
    }
  }
  // faces (max over 3 vertices, sign +1)
  {
    int s2 = max(start, N + E);
    int m = s2 + srow;
    for (; m + 64 < end; m += 128) {
      int fa = m - N - E, fb = fa + 64;
      int a0 = face[fa], a1 = face[F + fa], a2 = face[2 * F + fa];
      int b0 = face[fb], b1 = face[F + fb], b2 = face[2 * F + fb];
      float ha = fmaxf(fmaxf(dot3(a0), dot3(a1)), dot3(a2)); int ga  = batch[a0];
      float hb = fmaxf(fmaxf(dot3(b0), dot3(b1)), dot3(b2)); int gb2 = batch[b0];
      deposit(ha, ga, 1);
      deposit(hb, gb2, 1);
    }
    if (m < end) {
      int f = m - N - E;
      int n0 = face[f], n1 = face[F + f], n2 = face[2 * F + f];
      deposit(fmaxf(fmaxf(dot3(n0), dot3(n1)), dot3(n2)), batch[n0], 1);
    }
  }
  __syncthreads();
  int4* dst = (int4*)(partial + (size_t)bid * 8192);
  const int4* src = (const int4*)hist;
#pragma unroll
  for (int i = 0; i < 2; ++i)
    dst[tid + 1024 * i] = src[tid + 1024 * i];
}

// K2: tree reduce over chunks. 512 blocks: s = bid>>6 (0..7), cg = bid&63;
// cell cid = cg*256+tid; cid = hf*8192 + (arr*4096 + g*512 + bin*16 + t16).
// Plain coalesced loads/stores, no atomics.
__global__ __launch_bounds__(256) void reduce_kernel(const int* __restrict__ partial,
    int* __restrict__ part2) {
  int tid = threadIdx.x, bid = blockIdx.x;
  int s = bid >> 6, cg = bid & 63;
  int cid = cg * 256 + tid;
  int hf = cid >> 13, j = cid & 8191;
  int sum = 0;
  for (int cc = s; cc < NCH; cc += RSL)
    sum += partial[(size_t)(cc * 2 + hf) * 8192 + j];
  part2[s * 16384 + cid] = sum;
}

// K3: per-graph block (8 x 1024): sum RSL slices (plain loads), Hillis-Steele
// prefix of markers over bins, add fractional transitions, per-graph max,
// normalize, write out.
__global__ __launch_bounds__(1024) void fin_kernel(const int* __restrict__ part2,
    float* __restrict__ out) {
  __shared__ float sP[32][33];
  __shared__ float wmax[16];
  int g = blockIdx.x, tid = threadIdx.x;
  int b = tid >> 5, t = tid & 31;
  int hf = t >> 4, t16 = t & 15;
  int jc = (hf << 13) + (g << 9) + (b << 4) + t16;  // marker cell
  int ja = jc + 4096;                               // transition cell
  int sc = 0, sa = 0;
#pragma unroll
  for (int s = 0; s < RSL; ++s) {
    sc += part2[s * 16384 + jc];
    sa += part2[s * 16384 + ja];
  }
  sP[b][t] = (float)sc;
  __syncthreads();
#pragma unroll
  for (int st = 1; st < 32; st <<= 1) {
    float add = (b >= st) ? sP[b - st][t] : 0.f;
    __syncthreads();
    sP[b][t] += add;
    __syncthreads();
  }
  float r = sP[b][t] + (float)sa * (1.f / FPS);
  float m = r;
#pragma unroll
  for (int off = 32; off > 0; off >>= 1) m = fmaxf(m, __shfl_down(m, off));
  if ((tid & 63) == 0) wmax[tid >> 6] = m;
  __syncthreads();
  if (tid == 0) {
    float mm = wmax[0];
#pragma unroll
    for (int ww = 1; ww < 16; ++ww) mm = fmaxf(mm, wmax[ww]);
    wmax[0] = mm;
  }
  __syncthreads();
  out[(size_t)g * 1024 + tid] = r / wmax[0];
}

extern "C" void kernel_launch(void* const* d_in, const int* in_sizes, int n_in,
                              void* d_out, int out_size, void* d_ws, size_t ws_size,
                              hipStream_t stream) {
  const float* x     = (const float*)d_in[0];
  const float* v     = (const float*)d_in[1];
  const float* lin   = (const float*)d_in[2];
  const int*   ei    = (const int*)d_in[3];
  const int*   face  = (const int*)d_in[4];
  const int*   batch = (const int*)d_in[5];
  const int*   scale = (const int*)d_in[6];
  const int N = in_sizes[5];
  const int E = in_sizes[3] / 2;
  const int F = in_sizes[4] / 3;
  const int M = N + E + F;
  const int csz = (M + NCH - 1) / NCH;   // simplices per chunk (~704)

  int* partial = (int*)d_ws;                          // 2*NCH*8192 ints
  int* part2   = partial + (size_t)2 * NCH * 8192;    // RSL*16384 ints

  ect_kernel<<<2 * NCH, 1024, 0, stream>>>(x, v, ei, face, batch, lin, scale,
                                           partial, N, E, F, M, csz);
  reduce_kernel<<<64 * RSL, 256, 0, stream>>>(partial, part2);
  fin_kernel<<<8, 1024, 0, stream>>>(part2, (float*)d_out);
}